// Round 2
// 823.206 us; speedup vs baseline: 1.0723x; 1.0723x over previous
//
#include <hip/hip_runtime.h>

#define N_NODES 200000
#define DIM 64
#define BSHIFT 8                       // 256 rows per bucket
#define BROWS 256
#define NB 782                         // ceil(200000 / 256)
#define NB_PAD 1024
#define CHUNK 4096                     // edges per bucket_scatter block

__device__ __forceinline__ float bf2f(unsigned short u) {
    return __uint_as_float(((unsigned int)u) << 16);
}
__device__ __forceinline__ unsigned short f2bf(float f) {
    unsigned int u = __float_as_uint(f);
    u += 0x7FFFu + ((u >> 16) & 1u);   // round-to-nearest-even
    return (unsigned short)(u >> 16);
}

// ---- Pass A: bucket histogram (LDS-staged) ----
__global__ __launch_bounds__(256) void bucket_hist(const int* __restrict__ rows, int E,
                                                   int* __restrict__ bcnt) {
    __shared__ int h[NB_PAD];
    for (int i = threadIdx.x; i < NB_PAD; i += 256) h[i] = 0;
    __syncthreads();
    int stride = gridDim.x * blockDim.x;
    for (int e = blockIdx.x * blockDim.x + threadIdx.x; e < E; e += stride)
        atomicAdd(&h[rows[e] >> BSHIFT], 1);
    __syncthreads();
    for (int i = threadIdx.x; i < NB; i += 256)
        if (h[i]) atomicAdd(&bcnt[i], h[i]);
}

// ---- Pass B: wave-parallel exclusive scan of 782 bucket counts ----
__global__ __launch_bounds__(1024) void bucket_scan(const int* __restrict__ bcnt,
                                                    int* __restrict__ bbase,
                                                    int* __restrict__ bcur) {
    __shared__ int wsum[16];
    int t = threadIdx.x;
    int v = (t < NB) ? bcnt[t] : 0;
    int incl = v;
    for (int off = 1; off < 64; off <<= 1) {
        int u = __shfl_up(incl, off);
        if ((t & 63) >= off) incl += u;
    }
    if ((t & 63) == 63) wsum[t >> 6] = incl;
    __syncthreads();
    if (t < 16) {
        int w = wsum[t];
        for (int off = 1; off < 16; off <<= 1) {
            int u = __shfl_up(w, off);
            if (t >= off) w += u;
        }
        wsum[t] = w;                    // inclusive wave sums
    }
    __syncthreads();
    int wb = (t >= 64) ? wsum[(t >> 6) - 1] : 0;
    int excl = wb + incl - v;
    if (t < NB) { bbase[t] = excl; bcur[t] = excl; }
    if (t == NB - 1) bbase[NB] = excl + v;
}

// ---- Pass C: chunked scatter into bucket-grouped tmp, LDS-staged coalesced writes ----
// 512 threads; edges register-stashed (rows/cols/vals each read exactly once);
// 1024-bin scan via 2-level shuffle scan (~5 syncs vs 18 Hillis-Steele syncs).
__global__ __launch_bounds__(512) void bucket_scatter(const int* __restrict__ rows,
                                                      const int* __restrict__ cols,
                                                      const float* __restrict__ vals, int E,
                                                      int* __restrict__ bcur,
                                                      int2* __restrict__ tmp) {
    __shared__ int h[NB_PAD];          // counts, later reused as fix (g - excl)
    __shared__ int cur2[NB_PAD];       // block-local exclusive, then atomic cursor
    __shared__ int wtot[8];
    __shared__ int2 stage[CHUNK];
    __shared__ unsigned short sbkt[CHUNK];
    const int base = blockIdx.x * CHUNK;
    const int count = min(CHUNK, E - base);
    const int t = threadIdx.x;

    for (int i = t; i < NB_PAD; i += 512) h[i] = 0;
    __syncthreads();

    int myr[8], myc[8];
    float myv[8];
#pragma unroll
    for (int k = 0; k < 8; ++k) {
        int i = t + k * 512;
        if (i < count) {
            myr[k] = rows[base + i];
            myc[k] = cols[base + i];
            myv[k] = vals[base + i];
            atomicAdd(&h[myr[k] >> BSHIFT], 1);
        }
    }
    __syncthreads();

    // scan 1024 bins: 2 bins per thread, wave scan + cross-wave totals
    int h0 = h[2 * t], h1 = h[2 * t + 1];
    int s = h0 + h1;
    int incl = s;
    for (int off = 1; off < 64; off <<= 1) {
        int u = __shfl_up(incl, off);
        if ((t & 63) >= off) incl += u;
    }
    if ((t & 63) == 63) wtot[t >> 6] = incl;
    __syncthreads();
    int wb = 0;
    for (int w = 0; w < (t >> 6); ++w) wb += wtot[w];
    int excl = wb + incl - s;
    cur2[2 * t] = excl;
    cur2[2 * t + 1] = excl + h0;
    __syncthreads();

    // reserve global ranges; h becomes fix = g - excl
    for (int i = t; i < NB; i += 512) {
        int hi = h[i];
        int g = hi ? atomicAdd(&bcur[i], hi) : 0;
        h[i] = g - cur2[i];
    }
    __syncthreads();

    // stage in bucket-grouped order
#pragma unroll
    for (int k = 0; k < 8; ++k) {
        int i = t + k * 512;
        if (i < count) {
            int r = myr[k];
            int b = r >> BSHIFT;
            int slot = atomicAdd(&cur2[b], 1);
            stage[slot] = make_int2(((r & (BROWS - 1)) << 18) | myc[k], __float_as_int(myv[k]));
            sbkt[slot] = (unsigned short)b;
        }
    }
    __syncthreads();
    for (int s2 = t; s2 < count; s2 += 512)
        tmp[s2 + h[sbkt[s2]]] = stage[s2];
}

// ---- Pass D: per-bucket counting sort by row + row_start emission ----
// 782 blocks x 512 threads (~3 blocks/CU); shuffle scan, no serial t==0 loop.
__global__ __launch_bounds__(512) void bucket_sort(const int2* __restrict__ tmp,
                                                   const int* __restrict__ bbase,
                                                   int2* __restrict__ sorted,
                                                   int* __restrict__ row_start) {
    __shared__ int h[BROWS];           // counts, then atomic rank cursor
    __shared__ int hbase[BROWS];       // static exclusive base (row_start)
    __shared__ int wtot[4];
    const int b = blockIdx.x;
    const int s0 = bbase[b], s1 = bbase[b + 1];
    const int t = threadIdx.x;
    if (t < BROWS) h[t] = 0;
    __syncthreads();
    for (int e = s0 + t; e < s1; e += 512)
        atomicAdd(&h[tmp[e].x >> 18], 1);
    __syncthreads();
    int v = 0, incl = 0;
    if (t < BROWS) {
        v = h[t];
        incl = v;
        for (int off = 1; off < 64; off <<= 1) {
            int u = __shfl_up(incl, off);
            if ((t & 63) >= off) incl += u;
        }
        if ((t & 63) == 63) wtot[t >> 6] = incl;
    }
    __syncthreads();
    if (t < BROWS) {
        int wb = 0;
        for (int w = 0; w < (t >> 6); ++w) wb += wtot[w];
        hbase[t] = wb + incl - v;
    }
    __syncthreads();
    if (t < BROWS) {
        h[t] = hbase[t];
        int row = (b << BSHIFT) + t;
        if (row < N_NODES) row_start[row] = s0 + hbase[t];
    }
    if (b == NB - 1 && t == 0) row_start[N_NODES] = s1;
    __syncthreads();
    for (int e = s0 + t; e < s1; e += 512) {
        int2 kv = tmp[e];
        int r = kv.x >> 18;
        int rank = atomicAdd(&h[r], 1);
        sorted[s0 + rank] = make_int2(kv.x & 0x3FFFF, kv.y);
    }
}

// ---- fp32 -> bf16 convert (embeds -> xb0) ----
__global__ __launch_bounds__(256) void convert_kernel(const float* __restrict__ src,
                                                      unsigned short* __restrict__ dst, int n4) {
    int i = blockIdx.x * blockDim.x + threadIdx.x;
    if (i >= n4) return;
    float4 v = *(const float4*)(src + i * 4);
    ushort4 o;
    o.x = f2bf(v.x); o.y = f2bf(v.y); o.z = f2bf(v.z); o.w = f2bf(v.w);
    *(ushort4*)(dst + i * 4) = o;
}

// ---- SpMM pull-mode, bf16 gather: 8 threads/row, 8 feats (uint4=16B)/thread ----
// Software-pipelined: edge quad i+1 prefetched while quad i's gathers are in flight,
// collapsing the per-iter chain from (edge-latency + gather-latency) to ~gather-latency.
#define BF_LO(u) __uint_as_float((u) << 16)
#define BF_HI(u) __uint_as_float((u) & 0xFFFF0000u)
#define FMA8(G, V)                              \
    do {                                        \
        a0 = fmaf((V), BF_LO((G).x), a0);       \
        a1 = fmaf((V), BF_HI((G).x), a1);       \
        a2 = fmaf((V), BF_LO((G).y), a2);       \
        a3 = fmaf((V), BF_HI((G).y), a3);       \
        a4 = fmaf((V), BF_LO((G).z), a4);       \
        a5 = fmaf((V), BF_HI((G).z), a5);       \
        a6 = fmaf((V), BF_LO((G).w), a6);       \
        a7 = fmaf((V), BF_HI((G).w), a7);       \
    } while (0)

// MODE 0: y_bf = A*xb;  acc = embeds[r] + (A*xb)      (layer 1)
// MODE 1: y_bf = A*xb;  acc += A*xb                    (layers 2,3)
// MODE 2: acc = (acc + A*xb) * 0.2                     (layer 4, no y)
template <int MODE>
__global__ __launch_bounds__(256) void spmm_kernel(const int2* __restrict__ sorted,
                                                   const int* __restrict__ row_start,
                                                   const unsigned short* __restrict__ xb,
                                                   const float* __restrict__ embeds,
                                                   unsigned short* __restrict__ y,
                                                   float* __restrict__ acc) {
    int gid = blockIdx.x * blockDim.x + threadIdx.x;
    int r = gid >> 3;
    if (r >= N_NODES) return;
    int j = (gid & 7) << 3;
    const unsigned short* xbj = xb + j;
    int e = row_start[r], eend = row_start[r + 1];
    float a0 = 0.f, a1 = 0.f, a2 = 0.f, a3 = 0.f, a4 = 0.f, a5 = 0.f, a6 = 0.f, a7 = 0.f;

    int2 c0 = make_int2(0, 0), c1 = make_int2(0, 0);
    int2 c2 = make_int2(0, 0), c3 = make_int2(0, 0);
    if (e + 4 <= eend) {
        c0 = sorted[e]; c1 = sorted[e + 1]; c2 = sorted[e + 2]; c3 = sorted[e + 3];
    }
    while (e + 8 <= eend) {
        uint4 g0 = *(const uint4*)(xbj + (c0.x << 6));
        uint4 g1 = *(const uint4*)(xbj + (c1.x << 6));
        uint4 g2 = *(const uint4*)(xbj + (c2.x << 6));
        uint4 g3 = *(const uint4*)(xbj + (c3.x << 6));
        int2 n0 = sorted[e + 4], n1 = sorted[e + 5];
        int2 n2 = sorted[e + 6], n3 = sorted[e + 7];
        float v0 = __int_as_float(c0.y), v1 = __int_as_float(c1.y);
        float v2 = __int_as_float(c2.y), v3 = __int_as_float(c3.y);
        FMA8(g0, v0); FMA8(g1, v1); FMA8(g2, v2); FMA8(g3, v3);
        c0 = n0; c1 = n1; c2 = n2; c3 = n3;
        e += 4;
    }
    if (e + 4 <= eend) {               // last full quad (already loaded in c0..c3)
        uint4 g0 = *(const uint4*)(xbj + (c0.x << 6));
        uint4 g1 = *(const uint4*)(xbj + (c1.x << 6));
        uint4 g2 = *(const uint4*)(xbj + (c2.x << 6));
        uint4 g3 = *(const uint4*)(xbj + (c3.x << 6));
        float v0 = __int_as_float(c0.y), v1 = __int_as_float(c1.y);
        float v2 = __int_as_float(c2.y), v3 = __int_as_float(c3.y);
        FMA8(g0, v0); FMA8(g1, v1); FMA8(g2, v2); FMA8(g3, v3);
        e += 4;
    }
    for (; e < eend; ++e) {
        int2 cv = sorted[e];
        uint4 g = *(const uint4*)(xbj + (cv.x << 6));
        float v = __int_as_float(cv.y);
        FMA8(g, v);
    }

    int o = (r << 6) + j;
    if (MODE == 0) {
        uint4 yo;
        yo.x = (unsigned)f2bf(a0) | ((unsigned)f2bf(a1) << 16);
        yo.y = (unsigned)f2bf(a2) | ((unsigned)f2bf(a3) << 16);
        yo.z = (unsigned)f2bf(a4) | ((unsigned)f2bf(a5) << 16);
        yo.w = (unsigned)f2bf(a6) | ((unsigned)f2bf(a7) << 16);
        *(uint4*)(y + o) = yo;
        float4 x0 = *(const float4*)(embeds + o);
        float4 x1 = *(const float4*)(embeds + o + 4);
        *(float4*)(acc + o)     = make_float4(x0.x + a0, x0.y + a1, x0.z + a2, x0.w + a3);
        *(float4*)(acc + o + 4) = make_float4(x1.x + a4, x1.y + a5, x1.z + a6, x1.w + a7);
    } else if (MODE == 1) {
        uint4 yo;
        yo.x = (unsigned)f2bf(a0) | ((unsigned)f2bf(a1) << 16);
        yo.y = (unsigned)f2bf(a2) | ((unsigned)f2bf(a3) << 16);
        yo.z = (unsigned)f2bf(a4) | ((unsigned)f2bf(a5) << 16);
        yo.w = (unsigned)f2bf(a6) | ((unsigned)f2bf(a7) << 16);
        *(uint4*)(y + o) = yo;
        float4 q0 = *(const float4*)(acc + o);
        float4 q1 = *(const float4*)(acc + o + 4);
        *(float4*)(acc + o)     = make_float4(q0.x + a0, q0.y + a1, q0.z + a2, q0.w + a3);
        *(float4*)(acc + o + 4) = make_float4(q1.x + a4, q1.y + a5, q1.z + a6, q1.w + a7);
    } else {
        const float sc = 0.2f;
        float4 q0 = *(const float4*)(acc + o);
        float4 q1 = *(const float4*)(acc + o + 4);
        *(float4*)(acc + o)     = make_float4((q0.x + a0) * sc, (q0.y + a1) * sc,
                                              (q0.z + a2) * sc, (q0.w + a3) * sc);
        *(float4*)(acc + o + 4) = make_float4((q1.x + a4) * sc, (q1.y + a5) * sc,
                                              (q1.z + a6) * sc, (q1.w + a7) * sc);
    }
}

extern "C" void kernel_launch(void* const* d_in, const int* in_sizes, int n_in,
                              void* d_out, int out_size, void* d_ws, size_t ws_size,
                              hipStream_t stream) {
    const float* embeds = (const float*)d_in[0];
    const int*   rows   = (const int*)d_in[1];
    const int*   cols   = (const int*)d_in[2];
    const float* vals   = (const float*)d_in[3];
    float* acc = (float*)d_out;
    const int E = in_sizes[1];

    char* ws = (char*)d_ws;
    size_t off = 0;
    auto alloc = [&](size_t bytes) -> char* {
        char* p = ws + off;
        off = (off + bytes + 255) & ~(size_t)255;
        return p;
    };
    int*   bcnt      = (int*)alloc((size_t)NB * 4);
    int*   bbase     = (int*)alloc((size_t)(NB + 1) * 4);
    int*   bcur      = (int*)alloc((size_t)NB * 4);
    int*   row_start = (int*)alloc((size_t)(N_NODES + 1) * 4);
    int2*  sorted    = (int2*)alloc((size_t)E * 8);                          // 51.2 MB
    unsigned short* xb0 = (unsigned short*)alloc((size_t)N_NODES * DIM * 2); // 25.6 MB
    unsigned short* xb1 = (unsigned short*)alloc((size_t)N_NODES * DIM * 2); // 25.6 MB
    int2*  tmp       = (int2*)alloc((size_t)E * 8);                          // 51.2 MB

    hipMemsetAsync(bcnt, 0, (size_t)NB * 4, stream);

    bucket_hist<<<1024, 256, 0, stream>>>(rows, E, bcnt);
    bucket_scan<<<1, 1024, 0, stream>>>(bcnt, bbase, bcur);
    bucket_scatter<<<(E + CHUNK - 1) / CHUNK, 512, 0, stream>>>(rows, cols, vals, E, bcur, tmp);
    bucket_sort<<<NB, 512, 0, stream>>>(tmp, bbase, sorted, row_start);

    int n4 = N_NODES * DIM / 4;
    convert_kernel<<<(n4 + 255) / 256, 256, 0, stream>>>(embeds, xb0, n4);

    int sb = (N_NODES * 8 + 255) / 256;   // 8 threads per row
    spmm_kernel<0><<<sb, 256, 0, stream>>>(sorted, row_start, xb0, embeds, xb1, acc);
    spmm_kernel<1><<<sb, 256, 0, stream>>>(sorted, row_start, xb1, embeds, xb0, acc);
    spmm_kernel<1><<<sb, 256, 0, stream>>>(sorted, row_start, xb0, embeds, xb1, acc);
    spmm_kernel<2><<<sb, 256, 0, stream>>>(sorted, row_start, xb1, embeds, xb0, acc);
}